// Round 1
// baseline (855.955 us; speedup 1.0000x reference)
//
#include <hip/hip_runtime.h>

// Problem constants (from reference): E=32 experts, H=1024 hidden, F=512 ffn,
// T=1024 tokens, K=8 top-k.
#define NE     32
#define HD     1024
#define FF     512
#define NT     1024
#define TOPK   8
#define NPAIR  (NT * TOPK)      // 8192 (token, k) routing entries
#define BM     64               // row tile (entries per tile)
#define MAXTILES 160            // sum ceil(n_e/BM) <= 8192/64 + 31 = 159

// ---------------- workspace layout (ints) ----------------
// [0..31]    counts per expert
// [32..63]   cursor per expert (fill phase)
// [64]       num_tiles
// [65..97]   offsets (E+1)
// [128..287] tile_e
// [288..447] tile_m
// [512..8703]          tok_list (NPAIR)
// [8704..16895]        w_list   (NPAIR floats)
// [16896...]           A intermediate (NPAIR * FF floats = 16 MB)

__global__ void k_zero(float* __restrict__ out, int* __restrict__ meta) {
    int i = blockIdx.x * blockDim.x + threadIdx.x;
    if (i < NT * HD) out[i] = 0.f;
    if (i < 128) meta[i] = 0;   // counts + cursor + num_tiles
}

__global__ void k_count(const int* __restrict__ idx, int* __restrict__ counts) {
    int i = blockIdx.x * blockDim.x + threadIdx.x;
    if (i < NPAIR) atomicAdd(&counts[idx[i]], 1);
}

__global__ void k_scan(const int* __restrict__ counts, int* __restrict__ offsets,
                       int* __restrict__ tile_e, int* __restrict__ tile_m,
                       int* __restrict__ numt) {
    __shared__ int sc[NE];
    __shared__ int soff[NE + 1];
    __shared__ int ste[MAXTILES], stm[MAXTILES];
    __shared__ int snt;
    int tid = threadIdx.x;
    if (tid < NE) sc[tid] = counts[tid];
    __syncthreads();
    if (tid == 0) {
        int off = 0, nt = 0;
        for (int e = 0; e < NE; e++) {
            soff[e] = off;
            for (int s = 0; s < sc[e]; s += BM) { ste[nt] = e; stm[nt] = s; nt++; }
            off += sc[e];
        }
        soff[NE] = off;
        snt = nt;
    }
    __syncthreads();
    if (tid <= NE) offsets[tid] = soff[tid];
    if (tid == 0) *numt = snt;
    for (int i = tid; i < snt; i += blockDim.x) { tile_e[i] = ste[i]; tile_m[i] = stm[i]; }
}

__global__ void k_fill(const int* __restrict__ idx, const float* __restrict__ tkw,
                       const int* __restrict__ offsets, int* __restrict__ cursor,
                       int* __restrict__ tok_list, float* __restrict__ w_list) {
    int i = blockIdx.x * blockDim.x + threadIdx.x;
    if (i < NPAIR) {
        int e = idx[i];
        int pos = offsets[e] + atomicAdd(&cursor[e], 1);
        tok_list[pos] = i / TOPK;
        w_list[pos] = tkw[i];
    }
}

// GEMM1: A[row, c] = silu(gu_gate[row, c]) * gu_up[row, c], grouped by expert.
// Block: BM=64 rows x 32 act-cols (pairs gate col c and up col F+c in-block).
__global__ __launch_bounds__(256) void k_gemm1(
        const float* __restrict__ hs, const float* __restrict__ wgu,
        const int* __restrict__ offsets, const int* __restrict__ tile_e,
        const int* __restrict__ tile_m, const int* __restrict__ numt,
        const int* __restrict__ tok_list, float* __restrict__ A) {
    int tile = blockIdx.x;
    if (tile >= *numt) return;
    int e  = tile_e[tile];
    int m0 = tile_m[tile];
    int seg = offsets[e];
    int nrows = offsets[e + 1] - seg - m0;
    if (nrows > BM) nrows = BM;
    int c0 = blockIdx.y * 32;

    __shared__ float Xs[BM][17];
    __shared__ float Ws[64][17];
    __shared__ int   toks[BM];
    int tid = threadIdx.x;
    if (tid < BM) toks[tid] = (tid < nrows) ? tok_list[seg + m0 + tid] : -1;
    __syncthreads();

    int tx = tid & 15, ty = tid >> 4;
    float accg[4][2] = {{0.f}}, accu[4][2] = {{0.f}};

    for (int k0 = 0; k0 < HD; k0 += 16) {
        for (int l = tid; l < BM * 16; l += 256) {
            int r = l >> 4, kk = l & 15;
            int tk = toks[r];
            Xs[r][kk] = (tk >= 0) ? hs[(size_t)tk * HD + k0 + kk] : 0.f;
        }
        for (int l = tid; l < 64 * 16; l += 256) {
            int r = l >> 4, kk = l & 15;
            int gr = (r < 32) ? (c0 + r) : (FF + c0 + (r - 32));
            Ws[r][kk] = wgu[(size_t)e * 2 * FF * HD + (size_t)gr * HD + k0 + kk];
        }
        __syncthreads();
#pragma unroll
        for (int kk = 0; kk < 16; kk++) {
            float xv[4];
#pragma unroll
            for (int i = 0; i < 4; i++) xv[i] = Xs[ty * 4 + i][kk];
            float wg[2], wu[2];
#pragma unroll
            for (int j = 0; j < 2; j++) { wg[j] = Ws[tx * 2 + j][kk]; wu[j] = Ws[32 + tx * 2 + j][kk]; }
#pragma unroll
            for (int i = 0; i < 4; i++)
#pragma unroll
                for (int j = 0; j < 2; j++) {
                    accg[i][j] += xv[i] * wg[j];
                    accu[i][j] += xv[i] * wu[j];
                }
        }
        __syncthreads();
    }
#pragma unroll
    for (int i = 0; i < 4; i++) {
        int r = ty * 4 + i;
        if (r < nrows) {
#pragma unroll
            for (int j = 0; j < 2; j++) {
                float g = accg[i][j], u = accu[i][j];
                float act = (g / (1.f + __expf(-g))) * u;   // silu(g)*u
                A[(size_t)(seg + m0 + r) * FF + c0 + tx * 2 + j] = act;
            }
        }
    }
}

// GEMM2: out[token, n] += w * (A[row, :] . Wd[e][n, :]), atomic scatter-add.
__global__ __launch_bounds__(256) void k_gemm2(
        const float* __restrict__ A, const float* __restrict__ wd,
        const int* __restrict__ offsets, const int* __restrict__ tile_e,
        const int* __restrict__ tile_m, const int* __restrict__ numt,
        const int* __restrict__ tok_list, const float* __restrict__ w_list,
        float* __restrict__ out) {
    int tile = blockIdx.x;
    if (tile >= *numt) return;
    int e  = tile_e[tile];
    int m0 = tile_m[tile];
    int seg = offsets[e];
    int nrows = offsets[e + 1] - seg - m0;
    if (nrows > BM) nrows = BM;
    int n0 = blockIdx.y * 64;

    __shared__ float As[BM][17];
    __shared__ float Ws[64][17];
    int tid = threadIdx.x, tx = tid & 15, ty = tid >> 4;
    float acc[4][4] = {{0.f}};

    for (int k0 = 0; k0 < FF; k0 += 16) {
        for (int l = tid; l < BM * 16; l += 256) {
            int r = l >> 4, kk = l & 15;
            As[r][kk] = (r < nrows) ? A[(size_t)(seg + m0 + r) * FF + k0 + kk] : 0.f;
        }
        for (int l = tid; l < 64 * 16; l += 256) {
            int r = l >> 4, kk = l & 15;
            Ws[r][kk] = wd[(size_t)e * HD * FF + (size_t)(n0 + r) * FF + k0 + kk];
        }
        __syncthreads();
#pragma unroll
        for (int kk = 0; kk < 16; kk++) {
            float xv[4], wv[4];
#pragma unroll
            for (int i = 0; i < 4; i++) xv[i] = As[ty * 4 + i][kk];
#pragma unroll
            for (int j = 0; j < 4; j++) wv[j] = Ws[tx * 4 + j][kk];
#pragma unroll
            for (int i = 0; i < 4; i++)
#pragma unroll
                for (int j = 0; j < 4; j++) acc[i][j] += xv[i] * wv[j];
        }
        __syncthreads();
    }
#pragma unroll
    for (int i = 0; i < 4; i++) {
        int r = ty * 4 + i;
        if (r < nrows) {
            int   tk = tok_list[seg + m0 + r];
            float w  = w_list[seg + m0 + r];
#pragma unroll
            for (int j = 0; j < 4; j++)
                atomicAdd(&out[(size_t)tk * HD + n0 + tx * 4 + j], w * acc[i][j]);
        }
    }
}

extern "C" void kernel_launch(void* const* d_in, const int* in_sizes, int n_in,
                              void* d_out, int out_size, void* d_ws, size_t ws_size,
                              hipStream_t stream) {
    const float* hs  = (const float*)d_in[0];   // (T, H)
    const int*   idx = (const int*)  d_in[1];   // (T, K)
    const float* tkw = (const float*)d_in[2];   // (T, K)
    const float* wgu = (const float*)d_in[3];   // (E, 2F, H)
    const float* wd  = (const float*)d_in[4];   // (E, H, F)
    float* out = (float*)d_out;                 // (T, H)

    int* meta     = (int*)d_ws;
    int* counts   = meta;
    int* cursor   = meta + 32;
    int* numt     = meta + 64;
    int* offsets  = meta + 65;
    int* tile_e   = meta + 128;
    int* tile_m   = meta + 128 + MAXTILES;
    int* tok_list = meta + 512;
    float* w_list = (float*)(meta + 512 + NPAIR);
    float* A      = (float*)(meta + 512 + 2 * NPAIR);   // NPAIR*FF floats (16 MB)

    k_zero <<<(NT * HD + 255) / 256, 256, 0, stream>>>(out, meta);
    k_count<<<(NPAIR + 255) / 256, 256, 0, stream>>>(idx, counts);
    k_scan <<<1, 64, 0, stream>>>(counts, offsets, tile_e, tile_m, numt);
    k_fill <<<(NPAIR + 255) / 256, 256, 0, stream>>>(idx, tkw, offsets, cursor, tok_list, w_list);

    dim3 g1(MAXTILES, FF / 32);
    k_gemm1<<<g1, 256, 0, stream>>>(hs, wgu, offsets, tile_e, tile_m, numt, tok_list, A);
    dim3 g2(MAXTILES, HD / 64);
    k_gemm2<<<g2, 256, 0, stream>>>(A, wd, offsets, tile_e, tile_m, numt, tok_list, w_list, out);
}

// Round 2
// 161.307 us; speedup vs baseline: 5.3064x; 5.3064x over previous
//
#include <hip/hip_runtime.h>

// E=32 experts, H=1024 hidden, F=512 ffn, T=1024 tokens, K=8 top-k.
#define NE     32
#define HD     1024
#define FF     512
#define NT     1024
#define TOPK   8
#define NPAIR  (NT * TOPK)      // 8192 routed (token,k) rows
#define MAXT2  96               // max 128-row tiles: 8192/128 + 32

typedef __attribute__((ext_vector_type(8))) short  bf16x8;
typedef __attribute__((ext_vector_type(4))) float  f32x4;

__device__ __forceinline__ unsigned short f2bf_rne(float f) {
    unsigned u = __float_as_uint(f);
    u += 0x7FFFu + ((u >> 16) & 1u);
    return (unsigned short)(u >> 16);
}

// ============================ main (MFMA) path ============================
// ws layout (ints from base):
//   meta[0]=numt, meta[1..33]=offsets, meta[64..159]=tile_e, meta[160..255]=tile_m
//   meta[256..]=tok_list(8192), w_list(8192 f32) @ +8448, posmap(8192) @ +16640
// byte offsets: A_bf @128K (8MB) | hs_bf (2MB) | wgu_bf (64MB) | wd_bf (32MB) | O_rows f32 (32MB)

__global__ __launch_bounds__(1024) void k_route(const int* __restrict__ idx,
                                                const float* __restrict__ tkw,
                                                int* __restrict__ meta) {
    __shared__ int sc[NE], scur[NE], soff[NE + 1];
    __shared__ int ste[MAXT2], stm[MAXT2], snt;
    int tid = threadIdx.x;                      // tid == token
    if (tid < NE) { sc[tid] = 0; scur[tid] = 0; }
    __syncthreads();
    int e8[TOPK];
#pragma unroll
    for (int j = 0; j < TOPK; j++) { e8[j] = idx[tid * TOPK + j]; atomicAdd(&sc[e8[j]], 1); }
    __syncthreads();
    if (tid == 0) {
        int off = 0, nt = 0;
        for (int e = 0; e < NE; e++) {
            soff[e] = off;
            for (int s = 0; s < sc[e]; s += 128) { ste[nt] = e; stm[nt] = s; nt++; }
            off += sc[e];
        }
        soff[NE] = off; snt = nt;
    }
    __syncthreads();
    int*   tok_list = meta + 256;
    float* w_list   = (float*)(meta + 8448);
    int*   posmap   = meta + 16640;
#pragma unroll
    for (int j = 0; j < TOPK; j++) {
        int e = e8[j];
        int p = soff[e] + atomicAdd(&scur[e], 1);
        tok_list[p] = tid;
        w_list[p]   = tkw[tid * TOPK + j];
        posmap[tid * TOPK + j] = p;
    }
    if (tid <= NE) meta[1 + tid] = soff[tid];
    if (tid == 0)  meta[0] = snt;
    if (tid < MAXT2) { meta[64 + tid] = (tid < snt) ? ste[tid] : 0;
                       meta[160 + tid] = (tid < snt) ? stm[tid] : 0; }
}

__global__ void k_cvt(const float* __restrict__ hs, const float* __restrict__ wgu,
                      const float* __restrict__ wd, unsigned short* __restrict__ hs_bf,
                      unsigned short* __restrict__ wgu_bf, unsigned short* __restrict__ wd_bf) {
    const int HS4 = NT * HD / 4, GU4 = NE * 2 * FF * HD / 4, WD4 = NE * HD * FF / 4;
    const int total = HS4 + GU4 + WD4;
    for (int i = blockIdx.x * blockDim.x + threadIdx.x; i < total; i += gridDim.x * blockDim.x) {
        const float4* s; unsigned short* d; int j;
        if (i < HS4)            { s = (const float4*)hs;  d = hs_bf;  j = i; }
        else if (i < HS4 + GU4) { s = (const float4*)wgu; d = wgu_bf; j = i - HS4; }
        else                    { s = (const float4*)wd;  d = wd_bf;  j = i - HS4 - GU4; }
        float4 v = s[j];
        ushort4 o;
        o.x = f2bf_rne(v.x); o.y = f2bf_rne(v.y); o.z = f2bf_rne(v.z); o.w = f2bf_rne(v.w);
        ((ushort4*)d)[j] = o;
    }
}

// GEMM1: A[row, c] = silu(gate) * up * w_row, bf16 out. 128 rows x 64 act cols/block.
__global__ __launch_bounds__(256) void k_mm1(
        const unsigned short* __restrict__ hs_bf, const unsigned short* __restrict__ wgu_bf,
        const int* __restrict__ meta, unsigned short* __restrict__ A) {
    int numt = meta[0];
    int bx = blockIdx.x;
    if (bx >= numt) return;
    int e   = meta[64 + bx], m0 = meta[160 + bx];
    int seg = meta[1 + e];
    int nrows = meta[1 + e + 1] - seg - m0;
    if (nrows > 128) nrows = 128;
    int c0 = blockIdx.y * 64;
    const int* tok_list = meta + 256;
    const float* w_list = (const float*)(meta + 8448);

    __shared__ __align__(16) unsigned short Xs[128][40];
    __shared__ __align__(16) unsigned short Ws[128][40];
    __shared__ int   toks[128];
    __shared__ float wrow[128];
    int tid = threadIdx.x;
    if (tid < 128) {
        toks[tid] = (tid < nrows) ? tok_list[seg + m0 + tid] : -1;
        wrow[tid] = (tid < nrows) ? w_list[seg + m0 + tid] : 0.f;
    }
    __syncthreads();

    int wave = tid >> 6, lane = tid & 63, lr = lane & 15, lk = lane >> 4;
    f32x4 accg[2][4] = {}, accu[2][4] = {};
    const unsigned short* wbase = wgu_bf + (size_t)e * 2 * FF * HD;

    for (int k0 = 0; k0 < HD; k0 += 32) {
        for (int c = tid; c < 512; c += 256) {           // 512 16B-chunks per tile
            int r = c >> 2, cc = c & 3;
            int tk = toks[r];
            uint4 xv = make_uint4(0, 0, 0, 0);
            if (tk >= 0) xv = *(const uint4*)(hs_bf + (size_t)tk * HD + k0 + cc * 8);
            *(uint4*)&Xs[r][cc * 8] = xv;
            int grow = (r < 64) ? (c0 + r) : (FF + c0 + (r - 64));
            *(uint4*)&Ws[r][cc * 8] = *(const uint4*)(wbase + (size_t)grow * HD + k0 + cc * 8);
        }
        __syncthreads();
        bf16x8 a0 = *(const bf16x8*)&Xs[wave * 32 + lr][lk * 8];
        bf16x8 a1 = *(const bf16x8*)&Xs[wave * 32 + 16 + lr][lk * 8];
#pragma unroll
        for (int cf = 0; cf < 4; cf++) {
            bf16x8 bg = *(const bf16x8*)&Ws[cf * 16 + lr][lk * 8];
            bf16x8 bu = *(const bf16x8*)&Ws[64 + cf * 16 + lr][lk * 8];
            accg[0][cf] = __builtin_amdgcn_mfma_f32_16x16x32_bf16(a0, bg, accg[0][cf], 0, 0, 0);
            accg[1][cf] = __builtin_amdgcn_mfma_f32_16x16x32_bf16(a1, bg, accg[1][cf], 0, 0, 0);
            accu[0][cf] = __builtin_amdgcn_mfma_f32_16x16x32_bf16(a0, bu, accu[0][cf], 0, 0, 0);
            accu[1][cf] = __builtin_amdgcn_mfma_f32_16x16x32_bf16(a1, bu, accu[1][cf], 0, 0, 0);
        }
        __syncthreads();
    }
#pragma unroll
    for (int rf = 0; rf < 2; rf++)
#pragma unroll
        for (int q = 0; q < 4; q++) {
            int r = wave * 32 + rf * 16 + lk * 4 + q;
            if (r < nrows) {
                float w = wrow[r];
#pragma unroll
                for (int cf = 0; cf < 4; cf++) {
                    float g = accg[rf][cf][q], u = accu[rf][cf][q];
                    float act = (g / (1.f + __expf(-g))) * u * w;
                    A[(size_t)(seg + m0 + r) * FF + c0 + cf * 16 + lr] = f2bf_rne(act);
                }
            }
        }
}

// GEMM2: O_rows[row, n] = A[row,:] . Wd[e][n,:]. 128 rows x 128 out cols/block.
__global__ __launch_bounds__(256) void k_mm2(
        const unsigned short* __restrict__ A, const unsigned short* __restrict__ wd_bf,
        const int* __restrict__ meta, float* __restrict__ O) {
    int numt = meta[0];
    int bx = blockIdx.x;
    if (bx >= numt) return;
    int e   = meta[64 + bx], m0 = meta[160 + bx];
    int seg = meta[1 + e];
    int nrows = meta[1 + e + 1] - seg - m0;
    if (nrows > 128) nrows = 128;
    int n0 = blockIdx.y * 128;

    __shared__ __align__(16) unsigned short Xs[128][40];
    __shared__ __align__(16) unsigned short Ws[128][40];
    int tid = threadIdx.x;
    int wave = tid >> 6, lane = tid & 63, lr = lane & 15, lk = lane >> 4;
    f32x4 acc[2][8] = {};
    const unsigned short* wbase = wd_bf + (size_t)e * HD * FF;

    for (int k0 = 0; k0 < FF; k0 += 32) {
        for (int c = tid; c < 512; c += 256) {
            int r = c >> 2, cc = c & 3;
            uint4 xv = make_uint4(0, 0, 0, 0);
            if (r < nrows) xv = *(const uint4*)(A + (size_t)(seg + m0 + r) * FF + k0 + cc * 8);
            *(uint4*)&Xs[r][cc * 8] = xv;
            *(uint4*)&Ws[r][cc * 8] = *(const uint4*)(wbase + (size_t)(n0 + r) * FF + k0 + cc * 8);
        }
        __syncthreads();
        bf16x8 a0 = *(const bf16x8*)&Xs[wave * 32 + lr][lk * 8];
        bf16x8 a1 = *(const bf16x8*)&Xs[wave * 32 + 16 + lr][lk * 8];
#pragma unroll
        for (int cf = 0; cf < 8; cf++) {
            bf16x8 b = *(const bf16x8*)&Ws[cf * 16 + lr][lk * 8];
            acc[0][cf] = __builtin_amdgcn_mfma_f32_16x16x32_bf16(a0, b, acc[0][cf], 0, 0, 0);
            acc[1][cf] = __builtin_amdgcn_mfma_f32_16x16x32_bf16(a1, b, acc[1][cf], 0, 0, 0);
        }
        __syncthreads();
    }
    const int* tok_list = meta + 256; (void)tok_list;
#pragma unroll
    for (int rf = 0; rf < 2; rf++)
#pragma unroll
        for (int q = 0; q < 4; q++) {
            int r = wave * 32 + rf * 16 + lk * 4 + q;
            if (r < nrows) {
#pragma unroll
                for (int cf = 0; cf < 8; cf++)
                    O[(size_t)(seg + m0 + r) * HD + n0 + cf * 16 + lr] = acc[rf][cf][q];
            }
        }
}

__global__ void k_reduce(const float* __restrict__ O, const int* __restrict__ posmap,
                         float* __restrict__ out) {
    int i = blockIdx.x * blockDim.x + threadIdx.x;   // over NT*HD/4
    int t = i >> 8, c4 = i & 255;
    float4 acc = make_float4(0.f, 0.f, 0.f, 0.f);
#pragma unroll
    for (int k = 0; k < TOPK; k++) {
        int p = posmap[t * TOPK + k];
        float4 v = ((const float4*)(O + (size_t)p * HD))[c4];
        acc.x += v.x; acc.y += v.y; acc.z += v.z; acc.w += v.w;
    }
    ((float4*)out)[i] = acc;
}

// ============================ fallback (f32) path ============================
#define BMF 64
#define MAXTF 160
__global__ void k_zero_fb(float* __restrict__ out, int* __restrict__ meta) {
    int i = blockIdx.x * blockDim.x + threadIdx.x;
    if (i < NT * HD) out[i] = 0.f;
    if (i < 128) meta[i] = 0;
}
__global__ void k_count_fb(const int* __restrict__ idx, int* __restrict__ counts) {
    int i = blockIdx.x * blockDim.x + threadIdx.x;
    if (i < NPAIR) atomicAdd(&counts[idx[i]], 1);
}
__global__ void k_scan_fb(const int* __restrict__ counts, int* __restrict__ offsets,
                          int* __restrict__ tile_e, int* __restrict__ tile_m,
                          int* __restrict__ numt) {
    __shared__ int sc[NE]; __shared__ int soff[NE + 1];
    __shared__ int ste[MAXTF], stm[MAXTF]; __shared__ int snt;
    int tid = threadIdx.x;
    if (tid < NE) sc[tid] = counts[tid];
    __syncthreads();
    if (tid == 0) {
        int off = 0, nt = 0;
        for (int e = 0; e < NE; e++) {
            soff[e] = off;
            for (int s = 0; s < sc[e]; s += BMF) { ste[nt] = e; stm[nt] = s; nt++; }
            off += sc[e];
        }
        soff[NE] = off; snt = nt;
    }
    __syncthreads();
    if (tid <= NE) offsets[tid] = soff[tid];
    if (tid == 0) *numt = snt;
    for (int i = tid; i < snt; i += blockDim.x) { tile_e[i] = ste[i]; tile_m[i] = stm[i]; }
}
__global__ void k_fill_fb(const int* __restrict__ idx, const float* __restrict__ tkw,
                          const int* __restrict__ offsets, int* __restrict__ cursor,
                          int* __restrict__ tok_list, float* __restrict__ w_list) {
    int i = blockIdx.x * blockDim.x + threadIdx.x;
    if (i < NPAIR) {
        int e = idx[i];
        int pos = offsets[e] + atomicAdd(&cursor[e], 1);
        tok_list[pos] = i / TOPK;
        w_list[pos] = tkw[i];
    }
}
__global__ __launch_bounds__(256) void k_gemm1_fb(
        const float* __restrict__ hs, const float* __restrict__ wgu,
        const int* __restrict__ offsets, const int* __restrict__ tile_e,
        const int* __restrict__ tile_m, const int* __restrict__ numt,
        const int* __restrict__ tok_list, float* __restrict__ A) {
    int tile = blockIdx.x;
    if (tile >= *numt) return;
    int e = tile_e[tile], m0 = tile_m[tile], seg = offsets[e];
    int nrows = offsets[e + 1] - seg - m0;
    if (nrows > BMF) nrows = BMF;
    int c0 = blockIdx.y * 32;
    __shared__ float Xs[BMF][17];
    __shared__ float Ws2[64][17];
    __shared__ int toks[BMF];
    int tid = threadIdx.x;
    if (tid < BMF) toks[tid] = (tid < nrows) ? tok_list[seg + m0 + tid] : -1;
    __syncthreads();
    int tx = tid & 15, ty = tid >> 4;
    float accg[4][2] = {{0.f}}, accu[4][2] = {{0.f}};
    for (int k0 = 0; k0 < HD; k0 += 16) {
        for (int l = tid; l < BMF * 16; l += 256) {
            int r = l >> 4, kk = l & 15;
            int tk = toks[r];
            Xs[r][kk] = (tk >= 0) ? hs[(size_t)tk * HD + k0 + kk] : 0.f;
        }
        for (int l = tid; l < 64 * 16; l += 256) {
            int r = l >> 4, kk = l & 15;
            int gr = (r < 32) ? (c0 + r) : (FF + c0 + (r - 32));
            Ws2[r][kk] = wgu[(size_t)e * 2 * FF * HD + (size_t)gr * HD + k0 + kk];
        }
        __syncthreads();
#pragma unroll
        for (int kk = 0; kk < 16; kk++) {
            float xv[4];
#pragma unroll
            for (int i = 0; i < 4; i++) xv[i] = Xs[ty * 4 + i][kk];
            float wg[2], wu[2];
#pragma unroll
            for (int j = 0; j < 2; j++) { wg[j] = Ws2[tx * 2 + j][kk]; wu[j] = Ws2[32 + tx * 2 + j][kk]; }
#pragma unroll
            for (int i = 0; i < 4; i++)
#pragma unroll
                for (int j = 0; j < 2; j++) { accg[i][j] += xv[i] * wg[j]; accu[i][j] += xv[i] * wu[j]; }
        }
        __syncthreads();
    }
#pragma unroll
    for (int i = 0; i < 4; i++) {
        int r = ty * 4 + i;
        if (r < nrows) {
#pragma unroll
            for (int j = 0; j < 2; j++) {
                float g = accg[i][j], u = accu[i][j];
                A[(size_t)(seg + m0 + r) * FF + c0 + tx * 2 + j] = (g / (1.f + __expf(-g))) * u;
            }
        }
    }
}
__global__ __launch_bounds__(256) void k_gemm2_fb(
        const float* __restrict__ A, const float* __restrict__ wd,
        const int* __restrict__ offsets, const int* __restrict__ tile_e,
        const int* __restrict__ tile_m, const int* __restrict__ numt,
        const int* __restrict__ tok_list, const float* __restrict__ w_list,
        float* __restrict__ out) {
    int tile = blockIdx.x;
    if (tile >= *numt) return;
    int e = tile_e[tile], m0 = tile_m[tile], seg = offsets[e];
    int nrows = offsets[e + 1] - seg - m0;
    if (nrows > BMF) nrows = BMF;
    int n0 = blockIdx.y * 64;
    __shared__ float As[BMF][17];
    __shared__ float Ws2[64][17];
    int tid = threadIdx.x, tx = tid & 15, ty = tid >> 4;
    float acc[4][4] = {{0.f}};
    for (int k0 = 0; k0 < FF; k0 += 16) {
        for (int l = tid; l < BMF * 16; l += 256) {
            int r = l >> 4, kk = l & 15;
            As[r][kk] = (r < nrows) ? A[(size_t)(seg + m0 + r) * FF + k0 + kk] : 0.f;
        }
        for (int l = tid; l < 64 * 16; l += 256) {
            int r = l >> 4, kk = l & 15;
            Ws2[r][kk] = wd[(size_t)e * HD * FF + (size_t)(n0 + r) * FF + k0 + kk];
        }
        __syncthreads();
#pragma unroll
        for (int kk = 0; kk < 16; kk++) {
            float xv[4], wv[4];
#pragma unroll
            for (int i = 0; i < 4; i++) xv[i] = As[ty * 4 + i][kk];
#pragma unroll
            for (int j = 0; j < 4; j++) wv[j] = Ws2[tx * 4 + j][kk];
#pragma unroll
            for (int i = 0; i < 4; i++)
#pragma unroll
                for (int j = 0; j < 4; j++) acc[i][j] += xv[i] * wv[j];
        }
        __syncthreads();
    }
#pragma unroll
    for (int i = 0; i < 4; i++) {
        int r = ty * 4 + i;
        if (r < nrows) {
            int tk = tok_list[seg + m0 + r];
            float w = w_list[seg + m0 + r];
#pragma unroll
            for (int j = 0; j < 4; j++)
                atomicAdd(&out[(size_t)tk * HD + n0 + tx * 4 + j], w * acc[i][j]);
        }
    }
}

// ============================ launch ============================
extern "C" void kernel_launch(void* const* d_in, const int* in_sizes, int n_in,
                              void* d_out, int out_size, void* d_ws, size_t ws_size,
                              hipStream_t stream) {
    const float* hs  = (const float*)d_in[0];
    const int*   idx = (const int*)  d_in[1];
    const float* tkw = (const float*)d_in[2];
    const float* wgu = (const float*)d_in[3];
    const float* wd  = (const float*)d_in[4];
    float* out = (float*)d_out;

    const size_t OFF_A   = 128 * 1024;
    const size_t OFF_HS  = OFF_A  + (size_t)NPAIR * FF * 2;          // +8MB
    const size_t OFF_WGU = OFF_HS + (size_t)NT * HD * 2;             // +2MB
    const size_t OFF_WD  = OFF_WGU + (size_t)NE * 2 * FF * HD * 2;   // +64MB
    const size_t OFF_O   = OFF_WD  + (size_t)NE * HD * FF * 2;       // +32MB
    const size_t WS_MAIN = OFF_O   + (size_t)NPAIR * HD * 4;         // +32MB ≈ 138.1MB

    if (ws_size >= WS_MAIN) {
        char* ws = (char*)d_ws;
        int* meta = (int*)ws;
        unsigned short* A_bf   = (unsigned short*)(ws + OFF_A);
        unsigned short* hs_bf  = (unsigned short*)(ws + OFF_HS);
        unsigned short* wgu_bf = (unsigned short*)(ws + OFF_WGU);
        unsigned short* wd_bf  = (unsigned short*)(ws + OFF_WD);
        float* O_rows          = (float*)(ws + OFF_O);
        const int* posmap      = meta + 16640;

        k_route<<<1, 1024, 0, stream>>>(idx, tkw, meta);
        k_cvt<<<8192, 256, 0, stream>>>(hs, wgu, wd, hs_bf, wgu_bf, wd_bf);
        dim3 g1(MAXT2, FF / 64);
        k_mm1<<<g1, 256, 0, stream>>>(hs_bf, wgu_bf, meta, A_bf);
        dim3 g2(MAXT2, HD / 128);
        k_mm2<<<g2, 256, 0, stream>>>(A_bf, wd_bf, meta, O_rows);
        k_reduce<<<NT * HD / 4 / 256, 256, 0, stream>>>(O_rows, posmap, out);
    } else {
        // fallback: round-1 f32 path (needs ~16.2 MB)
        int* meta     = (int*)d_ws;
        int* counts   = meta;
        int* cursor   = meta + 32;
        int* numt     = meta + 64;
        int* offsets  = meta + 65;
        int* tile_e   = meta + 128;
        int* tile_m   = meta + 128 + MAXTF;
        int* tok_list = meta + 512;
        float* w_list = (float*)(meta + 512 + NPAIR);
        float* A      = (float*)(meta + 512 + 2 * NPAIR);

        k_zero_fb <<<(NT * HD + 255) / 256, 256, 0, stream>>>(out, meta);
        k_count_fb<<<(NPAIR + 255) / 256, 256, 0, stream>>>(idx, counts);
        k_scan_fb <<<1, 64, 0, stream>>>(counts, offsets, tile_e, tile_m, numt);
        k_fill_fb <<<(NPAIR + 255) / 256, 256, 0, stream>>>(idx, tkw, offsets, cursor, tok_list, w_list);
        dim3 g1(MAXTF, FF / 32);
        k_gemm1_fb<<<g1, 256, 0, stream>>>(hs, wgu, offsets, tile_e, tile_m, numt, tok_list, A);
        dim3 g2(MAXTF, HD / 64);
        k_gemm2_fb<<<g2, 256, 0, stream>>>(A, wd, offsets, tile_e, tile_m, numt, tok_list, w_list, out);
    }
}

// Round 3
// 133.594 us; speedup vs baseline: 6.4071x; 1.2074x over previous
//
#include <hip/hip_runtime.h>
#include <hip/hip_bf16.h>

// E=32 experts, H=1024 hidden, F=512 ffn, T=1024 tokens, K=8 top-k.
#define NE     32
#define HD     1024
#define FF     512
#define NT     1024
#define TOPK   8
#define NPAIR  (NT * TOPK)      // 8192 routed (token,k) rows
#define MAXT2  96               // max 128-row tiles: 8192/128 + 32

typedef __attribute__((ext_vector_type(8))) short  bf16x8;
typedef __attribute__((ext_vector_type(4))) float  f32x4;

__device__ __forceinline__ unsigned short f2bf_rne(float f) {
    unsigned u = __float_as_uint(f);
    u += 0x7FFFu + ((u >> 16) & 1u);
    return (unsigned short)(u >> 16);
}

// pack 2 f32 -> 2 bf16 (RNE) in one u32; compiler maps to v_cvt_pk_bf16_f32
__device__ __forceinline__ unsigned pk2(float x, float y) {
    __hip_bfloat162 h = __float22bfloat162_rn(float2{x, y});
    union { __hip_bfloat162 h; unsigned u; } c;
    c.h = h;
    return c.u;
}

// load 8 consecutive f32, return 8 bf16 packed in uint4
__device__ __forceinline__ uint4 pk8(const float* __restrict__ p) {
    float4 a = *(const float4*)p;
    float4 b = *(const float4*)(p + 4);
    uint4 r;
    r.x = pk2(a.x, a.y);
    r.y = pk2(a.z, a.w);
    r.z = pk2(b.x, b.y);
    r.w = pk2(b.z, b.w);
    return r;
}

// ---------------- workspace layout ----------------
// meta ints: [0]=numt, [1..33]=offsets, [64..159]=tile_e, [160..255]=tile_m,
//            [256..]=tok_list(8192), w_list(8192 f32) @ +8448, posmap @ +16640
// bytes: A_bf @128K (8MB bf16) | O_rows @128K+8M (32MB f32)   => ~40.2 MB

__global__ __launch_bounds__(1024) void k_route(const int* __restrict__ idx,
                                                const float* __restrict__ tkw,
                                                int* __restrict__ meta) {
    __shared__ int sc[NE], scur[NE], soff[NE + 1];
    __shared__ int ste[MAXT2], stm[MAXT2], snt;
    int tid = threadIdx.x;                      // tid == token
    if (tid < NE) { sc[tid] = 0; scur[tid] = 0; }
    __syncthreads();
    int e8[TOPK];
#pragma unroll
    for (int j = 0; j < TOPK; j++) { e8[j] = idx[tid * TOPK + j]; atomicAdd(&sc[e8[j]], 1); }
    __syncthreads();
    if (tid == 0) {
        int off = 0, nt = 0;
        for (int e = 0; e < NE; e++) {
            soff[e] = off;
            for (int s = 0; s < sc[e]; s += 128) { ste[nt] = e; stm[nt] = s; nt++; }
            off += sc[e];
        }
        soff[NE] = off; snt = nt;
    }
    __syncthreads();
    int*   tok_list = meta + 256;
    float* w_list   = (float*)(meta + 8448);
    int*   posmap   = meta + 16640;
#pragma unroll
    for (int j = 0; j < TOPK; j++) {
        int e = e8[j];
        int p = soff[e] + atomicAdd(&scur[e], 1);
        tok_list[p] = tid;
        w_list[p]   = tkw[tid * TOPK + j];
        posmap[tid * TOPK + j] = p;
    }
    if (tid <= NE) meta[1 + tid] = soff[tid];
    if (tid == 0)  meta[0] = snt;
    if (tid < MAXT2) { meta[64 + tid] = (tid < snt) ? ste[tid] : 0;
                       meta[160 + tid] = (tid < snt) ? stm[tid] : 0; }
}

// GEMM1: A[row, c] = silu(gate) * up * w_row, bf16 out. 128 rows x 64 act cols/block.
// Stages f32 hs (gathered) and f32 wgu with inline cvt_pk -> bf16 LDS.
__global__ __launch_bounds__(256) void k_mm1(
        const float* __restrict__ hs, const float* __restrict__ wgu,
        const int* __restrict__ meta, unsigned short* __restrict__ A) {
    int numt = meta[0];
    int bx = blockIdx.x;
    if (bx >= numt) return;
    int e   = meta[64 + bx], m0 = meta[160 + bx];
    int seg = meta[1 + e];
    int nrows = meta[1 + e + 1] - seg - m0;
    if (nrows > 128) nrows = 128;
    int c0 = blockIdx.y * 64;
    const int* tok_list = meta + 256;
    const float* w_list = (const float*)(meta + 8448);

    __shared__ __align__(16) unsigned short Xs[128][40];
    __shared__ __align__(16) unsigned short Ws[128][40];
    __shared__ int   toks[128];
    __shared__ float wrow[128];
    int tid = threadIdx.x;
    if (tid < 128) {
        toks[tid] = (tid < nrows) ? tok_list[seg + m0 + tid] : -1;
        wrow[tid] = (tid < nrows) ? w_list[seg + m0 + tid] : 0.f;
    }
    __syncthreads();

    int wave = tid >> 6, lane = tid & 63, lr = lane & 15, lk = lane >> 4;
    f32x4 accg[2][4] = {}, accu[2][4] = {};
    const float* wbase = wgu + (size_t)e * 2 * FF * HD;

    for (int k0 = 0; k0 < HD; k0 += 32) {
        for (int c = tid; c < 512; c += 256) {           // 512 8-elem chunks/tile
            int r = c >> 2, cc = c & 3;
            int tk = toks[r];
            uint4 xv = make_uint4(0, 0, 0, 0);
            if (tk >= 0) xv = pk8(hs + (size_t)tk * HD + k0 + cc * 8);
            *(uint4*)&Xs[r][cc * 8] = xv;
            int grow = (r < 64) ? (c0 + r) : (FF + c0 + (r - 64));
            *(uint4*)&Ws[r][cc * 8] = pk8(wbase + (size_t)grow * HD + k0 + cc * 8);
        }
        __syncthreads();
        bf16x8 a0 = *(const bf16x8*)&Xs[wave * 32 + lr][lk * 8];
        bf16x8 a1 = *(const bf16x8*)&Xs[wave * 32 + 16 + lr][lk * 8];
#pragma unroll
        for (int cf = 0; cf < 4; cf++) {
            bf16x8 bg = *(const bf16x8*)&Ws[cf * 16 + lr][lk * 8];
            bf16x8 bu = *(const bf16x8*)&Ws[64 + cf * 16 + lr][lk * 8];
            accg[0][cf] = __builtin_amdgcn_mfma_f32_16x16x32_bf16(a0, bg, accg[0][cf], 0, 0, 0);
            accg[1][cf] = __builtin_amdgcn_mfma_f32_16x16x32_bf16(a1, bg, accg[1][cf], 0, 0, 0);
            accu[0][cf] = __builtin_amdgcn_mfma_f32_16x16x32_bf16(a0, bu, accu[0][cf], 0, 0, 0);
            accu[1][cf] = __builtin_amdgcn_mfma_f32_16x16x32_bf16(a1, bu, accu[1][cf], 0, 0, 0);
        }
        __syncthreads();
    }
#pragma unroll
    for (int rf = 0; rf < 2; rf++)
#pragma unroll
        for (int q = 0; q < 4; q++) {
            int r = wave * 32 + rf * 16 + lk * 4 + q;
            if (r < nrows) {
                float w = wrow[r];
#pragma unroll
                for (int cf = 0; cf < 4; cf++) {
                    float g = accg[rf][cf][q], u = accu[rf][cf][q];
                    float act = (g / (1.f + __expf(-g))) * u * w;
                    A[(size_t)(seg + m0 + r) * FF + c0 + cf * 16 + lr] = f2bf_rne(act);
                }
            }
        }
}

// GEMM2: O_rows[row, n] = A[row,:] . Wd[e][n,:]. 128 rows x 128 out cols/block.
// A is bf16 (direct stage); Wd is f32 (inline cvt).
__global__ __launch_bounds__(256) void k_mm2(
        const unsigned short* __restrict__ A, const float* __restrict__ wd,
        const int* __restrict__ meta, float* __restrict__ O) {
    int numt = meta[0];
    int bx = blockIdx.x;
    if (bx >= numt) return;
    int e   = meta[64 + bx], m0 = meta[160 + bx];
    int seg = meta[1 + e];
    int nrows = meta[1 + e + 1] - seg - m0;
    if (nrows > 128) nrows = 128;
    int n0 = blockIdx.y * 128;

    __shared__ __align__(16) unsigned short Xs[128][40];
    __shared__ __align__(16) unsigned short Ws[128][40];
    int tid = threadIdx.x;
    int wave = tid >> 6, lane = tid & 63, lr = lane & 15, lk = lane >> 4;
    f32x4 acc[2][8] = {};
    const float* wbase = wd + (size_t)e * HD * FF;

    for (int k0 = 0; k0 < FF; k0 += 32) {
        for (int c = tid; c < 512; c += 256) {
            int r = c >> 2, cc = c & 3;
            uint4 xv = make_uint4(0, 0, 0, 0);
            if (r < nrows) xv = *(const uint4*)(A + (size_t)(seg + m0 + r) * FF + k0 + cc * 8);
            *(uint4*)&Xs[r][cc * 8] = xv;
            *(uint4*)&Ws[r][cc * 8] = pk8(wbase + (size_t)(n0 + r) * FF + k0 + cc * 8);
        }
        __syncthreads();
        bf16x8 a0 = *(const bf16x8*)&Xs[wave * 32 + lr][lk * 8];
        bf16x8 a1 = *(const bf16x8*)&Xs[wave * 32 + 16 + lr][lk * 8];
#pragma unroll
        for (int cf = 0; cf < 8; cf++) {
            bf16x8 b = *(const bf16x8*)&Ws[cf * 16 + lr][lk * 8];
            acc[0][cf] = __builtin_amdgcn_mfma_f32_16x16x32_bf16(a0, b, acc[0][cf], 0, 0, 0);
            acc[1][cf] = __builtin_amdgcn_mfma_f32_16x16x32_bf16(a1, b, acc[1][cf], 0, 0, 0);
        }
        __syncthreads();
    }
#pragma unroll
    for (int rf = 0; rf < 2; rf++)
#pragma unroll
        for (int q = 0; q < 4; q++) {
            int r = wave * 32 + rf * 16 + lk * 4 + q;
            if (r < nrows) {
#pragma unroll
                for (int cf = 0; cf < 8; cf++)
                    O[(size_t)(seg + m0 + r) * HD + n0 + cf * 16 + lr] = acc[rf][cf][q];
            }
        }
}

__global__ void k_reduce(const float* __restrict__ O, const int* __restrict__ posmap,
                         float* __restrict__ out) {
    int i = blockIdx.x * blockDim.x + threadIdx.x;   // over NT*HD/4
    int t = i >> 8, c4 = i & 255;
    float4 acc = make_float4(0.f, 0.f, 0.f, 0.f);
#pragma unroll
    for (int k = 0; k < TOPK; k++) {
        int p = posmap[t * TOPK + k];
        float4 v = ((const float4*)(O + (size_t)p * HD))[c4];
        acc.x += v.x; acc.y += v.y; acc.z += v.z; acc.w += v.w;
    }
    ((float4*)out)[i] = acc;
}

// ============================ launch ============================
extern "C" void kernel_launch(void* const* d_in, const int* in_sizes, int n_in,
                              void* d_out, int out_size, void* d_ws, size_t ws_size,
                              hipStream_t stream) {
    const float* hs  = (const float*)d_in[0];   // (T, H)
    const int*   idx = (const int*)  d_in[1];   // (T, K)
    const float* tkw = (const float*)d_in[2];   // (T, K)
    const float* wgu = (const float*)d_in[3];   // (E, 2F, H)
    const float* wd  = (const float*)d_in[4];   // (E, H, F)
    float* out = (float*)d_out;                 // (T, H)

    const size_t OFF_A = 128 * 1024;
    const size_t OFF_O = OFF_A + (size_t)NPAIR * FF * 2;   // +8MB
    // total: OFF_O + NPAIR*HD*4 ≈ 40.2 MB

    char* ws = (char*)d_ws;
    int* meta = (int*)ws;
    unsigned short* A_bf = (unsigned short*)(ws + OFF_A);
    float* O_rows        = (float*)(ws + OFF_O);
    const int* posmap    = meta + 16640;

    k_route<<<1, 1024, 0, stream>>>(idx, tkw, meta);
    dim3 g1(MAXT2, FF / 64);
    k_mm1<<<g1, 256, 0, stream>>>(hs, wgu, meta, A_bf);
    dim3 g2(MAXT2, HD / 128);
    k_mm2<<<g2, 256, 0, stream>>>(A_bf, wd, meta, O_rows);
    k_reduce<<<NT * HD / 4 / 256, 256, 0, stream>>>(O_rows, posmap, out);
}